// Round 2
// baseline (325.478 us; speedup 1.0000x reference)
//
#include <hip/hip_runtime.h>
#include <hip/hip_bf16.h>
#include <math.h>

#define DIM 128
#define DFF 512
#define TTW 64
#define NPI 8
#define NTOK 9
#define TILE_H 32

typedef __attribute__((ext_vector_type(8))) short short8;
typedef __attribute__((ext_vector_type(4))) float float4v;

__device__ __forceinline__ float bf16lo_f32(unsigned u) {
    union { unsigned u; float f; } v; v.u = u << 16;
    return v.f;
}
__device__ __forceinline__ float bf16hi_f32(unsigned u) {
    union { unsigned u; float f; } v; v.u = u & 0xffff0000u;
    return v.f;
}
__device__ __forceinline__ unsigned pk_bf16(float a, float b) {  // -> a | b<<16
    __hip_bfloat162 h = __float22bfloat162_rn(float2{a, b});
    union { __hip_bfloat162 h; unsigned u; } cv; cv.h = h;
    return cv.u;
}

// ============ prep (slim): hf->bf16 (8 elems/thread) + W1/W2 transposes ============
__global__ __launch_bounds__(256)
void prep_k(const float* __restrict__ hf, const float* __restrict__ W1,
            const float* __restrict__ W2,
            unsigned short* __restrict__ hf2, unsigned short* __restrict__ w1t,
            unsigned short* __restrict__ w2t,
            int n_hf, int B_HF)
{
    __shared__ float tile[32][33];
    const int b = blockIdx.x, t = threadIdx.x;
    if (b < B_HF) {
        int i = (b * 256 + t) * 8;
        if (i < n_hf) {
            float4v v0 = *(const float4v*)(hf + i);
            float4v v1 = *(const float4v*)(hf + i + 4);
            uint4 o;
            o.x = pk_bf16(v0[0], v0[1]);
            o.y = pk_bf16(v0[2], v0[3]);
            o.z = pk_bf16(v1[0], v1[1]);
            o.w = pk_bf16(v1[2], v1[3]);
            *(uint4*)(hf2 + i) = o;
        }
    } else if (b < B_HF + 64) {
        const int tb = b - B_HF;            // W1 [128][512] -> w1t bf16 [512][128]
        const int r0 = (tb & 3) * 32, c0 = (tb >> 2) * 32;
        const int ty = t >> 3, tx = t & 7;
        *(float4v*)&tile[ty][tx * 4] = *(const float4v*)(W1 + (r0 + ty) * DFF + c0 + tx * 4);
        __syncthreads();
        uint2 o;
        o.x = pk_bf16(tile[tx * 4 + 0][ty], tile[tx * 4 + 1][ty]);
        o.y = pk_bf16(tile[tx * 4 + 2][ty], tile[tx * 4 + 3][ty]);
        *(uint2*)(w1t + (c0 + ty) * DIM + r0 + tx * 4) = o;
    } else {
        const int tb = b - B_HF - 64;       // W2 [512][64] -> w2t bf16 [64][512]
        const int r0 = (tb & 15) * 32, c0 = (tb >> 4) * 32;
        const int ty = t >> 3, tx = t & 7;
        *(float4v*)&tile[ty][tx * 4] = *(const float4v*)(W2 + (r0 + ty) * TTW + c0 + tx * 4);
        __syncthreads();
        uint2 o;
        o.x = pk_bf16(tile[tx * 4 + 0][ty], tile[tx * 4 + 1][ty]);
        o.y = pk_bf16(tile[tx * 4 + 2][ty], tile[tx * 4 + 3][ty]);
        *(uint2*)(w2t + (c0 + ty) * DFF + r0 + tx * 4) = o;
    }
}

// ===== fused: gather+pool -> GEMM1 -> reg-LN (packed early) -> k-split GEMM2 =====
// R0: LDS 43008 -> 3 blocks/CU, Occ 30%, latency-bound (MfmaUtil 6.5%).
// R1: k-split halved Hsm (LDS 26624) but __launch_bounds__(256,6) (cap ~85 VGPR)
//     spilled acc[8][2] (WRITE_SIZE 25->465 MB, VGPR_Count 40) because the
//     k-split keeps acc[4..7] live through chunk-0 GEMM2 (~100 VGPR demand).
// R2: (256,5) (cap ~102) + pre-pack LN output to bf16 uint2 pk[8][2] (32 regs)
//     BEFORE the chunk loop, killing the 64-reg fp32 acc early. If WRITE_SIZE
//     jumps again -> back off to (256,4).
__global__ __launch_bounds__(256, 5)
void fused_k(const unsigned short* __restrict__ hf2,
             const float* __restrict__ w_q,
             const int* __restrict__ pi,
             const int* __restrict__ stats,
             const int* __restrict__ po,
             const unsigned short* __restrict__ w1t,     // bf16 [512][128]
             const float* __restrict__ b1,
             const float* __restrict__ gamma,
             const float* __restrict__ beta,
             const unsigned short* __restrict__ w2t,     // bf16 [64][512]
             const float* __restrict__ b2,
             float* __restrict__ out,
             int H)
{
    __shared__ __align__(16) unsigned short Apool[TILE_H][DIM + 8];   // 8704 B
    __shared__ __align__(16) unsigned short Hsm[TILE_H][256 + 8];     // 16896 B
    __shared__ float part[2][16][4][2];                 // [ht][row][wave][sum,ssq]

    const int t    = threadIdx.x;
    const int lane = t & 63;
    const int w    = t >> 6;
    const int row  = lane & 15;
    const int quad = lane >> 4;
    const int hop0 = blockIdx.x * TILE_H;

    // -------- Phase 1: gather + masked attention pooling (32 lanes/hop) --------
    {
        const int g = t >> 5, l = t & 31;       // lane l owns dims 4l..4l+3
        const float4v wq4 = *(const float4v*)(w_q + l * 4);

        int idxs[4][NTOK];
        unsigned vm[4];
        #pragma unroll
        for (int it = 0; it < 4; ++it) {
            int hop = hop0 + g + it * 8;
            if (hop >= H) hop = H - 1;          // clamp; out stores are guarded
            int4 p0 = *(const int4*)(pi + hop * NPI);
            int4 p1 = *(const int4*)(pi + hop * NPI + 4);
            int4 s0 = *(const int4*)(stats + hop * NPI);
            int4 s1 = *(const int4*)(stats + hop * NPI + 4);
            idxs[it][0] = p0.x; idxs[it][1] = p0.y;
            idxs[it][2] = p0.z; idxs[it][3] = p0.w;
            idxs[it][4] = p1.x; idxs[it][5] = p1.y;
            idxs[it][6] = p1.z; idxs[it][7] = p1.w;
            idxs[it][8] = po[hop];
            vm[it] = (s0.x != -1 ? 1u   : 0u) | (s0.y != -1 ? 2u   : 0u)
                   | (s0.z != -1 ? 4u   : 0u) | (s0.w != -1 ? 8u   : 0u)
                   | (s1.x != -1 ? 16u  : 0u) | (s1.y != -1 ? 32u  : 0u)
                   | (s1.z != -1 ? 64u  : 0u) | (s1.w != -1 ? 128u : 0u)
                   | 256u;                      // PO always valid
        }
        uint2 tu[4][NTOK];
        #pragma unroll
        for (int it = 0; it < 4; ++it)
            #pragma unroll
            for (int p = 0; p < NTOK; ++p)
                tu[it][p] = *(const uint2*)(hf2 + (size_t)idxs[it][p] * DIM + l * 4);

        #pragma unroll
        for (int it = 0; it < 4; ++it) {
            const int hl = g + it * 8;
            float tok[NTOK][4];
            #pragma unroll
            for (int p = 0; p < NTOK; ++p) {
                tok[p][0] = bf16lo_f32(tu[it][p].x);
                tok[p][1] = bf16hi_f32(tu[it][p].x);
                tok[p][2] = bf16lo_f32(tu[it][p].y);
                tok[p][3] = bf16hi_f32(tu[it][p].y);
            }
            float sc[NTOK];
            #pragma unroll
            for (int p = 0; p < NTOK; ++p)
                sc[p] = tok[p][0]*wq4[0] + tok[p][1]*wq4[1]
                      + tok[p][2]*wq4[2] + tok[p][3]*wq4[3];
            #pragma unroll
            for (int m = 1; m < 32; m <<= 1) {
                #pragma unroll
                for (int p = 0; p < NTOK; ++p) sc[p] += __shfl_xor(sc[p], m);
            }
            const float isd = 0.08838834764831845f;   // 1/sqrt(128)
            float mx = -1e30f;
            #pragma unroll
            for (int p = 0; p < NTOK; ++p) {
                sc[p] = ((vm[it] >> p) & 1u) ? sc[p] * isd : -1e30f;
                mx = fmaxf(mx, sc[p]);
            }
            float se = 0.f;
            #pragma unroll
            for (int p = 0; p < NTOK; ++p) { sc[p] = __expf(sc[p] - mx); se += sc[p]; }
            const float inv = 1.f / se;
            float a0=0.f, a1=0.f, a2=0.f, a3=0.f;
            #pragma unroll
            for (int p = 0; p < NTOK; ++p) {
                float a = sc[p] * inv;
                a0 += a * tok[p][0]; a1 += a * tok[p][1];
                a2 += a * tok[p][2]; a3 += a * tok[p][3];
            }
            uint2 o;
            o.x = pk_bf16(a0, a1);
            o.y = pk_bf16(a2, a3);
            *(uint2*)&Apool[hl][l * 4] = o;
        }
    }
    __syncthreads();

    // -------- GEMM1: A=W1T rows (out-dims, striped mt*64+w*16), B=Apool^T --------
    float4v acc[8][2];
    #pragma unroll
    for (int mt = 0; mt < 8; ++mt) {
        acc[mt][0] = (float4v){0.f, 0.f, 0.f, 0.f};
        acc[mt][1] = (float4v){0.f, 0.f, 0.f, 0.f};
    }
    {
        short8 bfr[2][4];
        #pragma unroll
        for (int ks = 0; ks < 4; ++ks) {
            const int k0 = ks * 32 + quad * 8;
            #pragma unroll
            for (int ht = 0; ht < 2; ++ht)
                bfr[ht][ks] = *(const short8*)&Apool[ht * 16 + row][k0];
        }
        #pragma unroll
        for (int mt = 0; mt < 8; ++mt) {
            const unsigned short* wrow = w1t + (size_t)(mt * 64 + w * 16 + row) * DIM;
            #pragma unroll
            for (int ks = 0; ks < 4; ++ks) {
                short8 afr = *(const short8*)(wrow + ks * 32 + quad * 8);
                acc[mt][0] = __builtin_amdgcn_mfma_f32_16x16x32_bf16(afr, bfr[0][ks], acc[mt][0], 0, 0, 0);
                acc[mt][1] = __builtin_amdgcn_mfma_f32_16x16x32_bf16(afr, bfr[1][ks], acc[mt][1], 0, 0, 0);
            }
        }
    }
    // -------- pass 1: bias + ReLU in registers, LN stats --------
    float sum0 = 0.f, ssq0 = 0.f, sum1 = 0.f, ssq1 = 0.f;
    #pragma unroll
    for (int mt = 0; mt < 8; ++mt) {
        const int nb = mt * 64 + w * 16 + quad * 4;
        const float4v bias = *(const float4v*)(b1 + nb);
        #pragma unroll
        for (int r = 0; r < 4; ++r) {
            float v0 = fmaxf(acc[mt][0][r] + bias[r], 0.f);
            float v1 = fmaxf(acc[mt][1][r] + bias[r], 0.f);
            acc[mt][0][r] = v0;  sum0 += v0;  ssq0 += v0 * v0;
            acc[mt][1][r] = v1;  sum1 += v1;  ssq1 += v1 * v1;
        }
    }
    #pragma unroll
    for (int m = 16; m <= 32; m <<= 1) {       // reduce across the 4 quads
        sum0 += __shfl_xor(sum0, m);  ssq0 += __shfl_xor(ssq0, m);
        sum1 += __shfl_xor(sum1, m);  ssq1 += __shfl_xor(ssq1, m);
    }
    if (lane < 16) {
        part[0][row][w][0] = sum0;  part[0][row][w][1] = ssq0;
        part[1][row][w][0] = sum1;  part[1][row][w][1] = ssq1;
    }
    __syncthreads();
    float mu[2], rs[2];
    #pragma unroll
    for (int ht = 0; ht < 2; ++ht) {
        float S = 0.f, Q = 0.f;
        #pragma unroll
        for (int ww = 0; ww < 4; ++ww) {
            S += part[ht][row][ww][0];
            Q += part[ht][row][ww][1];
        }
        const float invn = 1.f / (float)DFF;
        mu[ht] = S * invn;
        float var = Q * invn - mu[ht] * mu[ht];
        rs[ht] = rsqrtf(var + 1e-5f);
    }
    // -------- pass 2: normalize ALL dims now, pack bf16 -> pk[8][2] (32 regs);
    //          fp32 acc (64 regs) dies here, BEFORE the chunk loop. --------
    uint2 pk[8][2];
    #pragma unroll
    for (int mt = 0; mt < 8; ++mt) {
        const int nb = mt * 64 + w * 16 + quad * 4;
        const float4v g4  = *(const float4v*)(gamma + nb);
        const float4v be4 = *(const float4v*)(beta + nb);
        #pragma unroll
        for (int ht = 0; ht < 2; ++ht) {
            float o[4];
            #pragma unroll
            for (int r = 0; r < 4; ++r) {
                float tg = rs[ht] * g4[r];
                o[r] = acc[mt][ht][r] * tg + (be4[r] - mu[ht] * tg);
            }
            pk[mt][ht].x = pk_bf16(o[0], o[1]);
            pk[mt][ht].y = pk_bf16(o[2], o[3]);
        }
    }
    // -------- GEMM2, k-split into two 256-wide chunks through half-width Hsm ----
    {
        float4v acc2[2];
        acc2[0] = (float4v){0.f,0.f,0.f,0.f};
        acc2[1] = (float4v){0.f,0.f,0.f,0.f};
        #pragma unroll
        for (int c = 0; c < 2; ++c) {
            #pragma unroll
            for (int m4 = 0; m4 < 4; ++m4) {
                const int col = m4 * 64 + w * 16 + quad * 4;    // col within chunk
                *(uint2*)&Hsm[0 * 16 + row][col] = pk[c * 4 + m4][0];
                *(uint2*)&Hsm[1 * 16 + row][col] = pk[c * 4 + m4][1];
            }
            __syncthreads();
            // accumulate this k-chunk: A=Hsm [hop][k] LDS, B=w2t [tt][k] global
            const unsigned short* w2row = w2t + (size_t)(w * 16 + row) * DFF + c * 256;
            #pragma unroll
            for (int ks = 0; ks < 8; ++ks) {
                const int k0 = ks * 32 + quad * 8;
                short8 bfr = *(const short8*)(w2row + k0);
                #pragma unroll
                for (int mt = 0; mt < 2; ++mt) {
                    short8 afr = *(const short8*)&Hsm[mt * 16 + row][k0];
                    acc2[mt] = __builtin_amdgcn_mfma_f32_16x16x32_bf16(
                        afr, bfr, acc2[mt], 0, 0, 0);
                }
            }
            if (c == 0) __syncthreads();   // all reads done before chunk-1 writes
        }
        const float bb = b2[w * 16 + row];
        #pragma unroll
        for (int mt = 0; mt < 2; ++mt) {
            #pragma unroll
            for (int r = 0; r < 4; ++r) {
                int hop = hop0 + mt * 16 + quad * 4 + r;
                if (hop < H)
                    out[(size_t)hop * TTW + w * 16 + row] = acc2[mt][r] + bb;
            }
        }
    }
}

extern "C" void kernel_launch(void* const* d_in, const int* in_sizes, int n_in,
                              void* d_out, int out_size, void* d_ws, size_t ws_size,
                              hipStream_t stream) {
    const float* hf    = (const float*)d_in[0];
    const float* w_q   = (const float*)d_in[1];
    const float* W1    = (const float*)d_in[2];
    const float* b1    = (const float*)d_in[3];
    const float* gamma = (const float*)d_in[4];
    const float* beta  = (const float*)d_in[5];
    const float* W2    = (const float*)d_in[6];
    const float* b2    = (const float*)d_in[7];
    const int* pi      = (const int*)d_in[8];
    const int* stats   = (const int*)d_in[9];
    const int* po      = (const int*)d_in[10];
    float* out         = (float*)d_out;

    const int n_hf = in_sizes[0];           // N_NODES*128
    const int H    = in_sizes[10];
    const int ntiles = (H + TILE_H - 1) / TILE_H;

    // ws layout
    char* ws = (char*)d_ws;
    unsigned short* w1t = (unsigned short*)ws;                       // 128KB
    unsigned short* w2t = (unsigned short*)(ws + 131072);            // 64KB
    unsigned short* hf2 = (unsigned short*)(ws + 196608);            // n_hf*2

    const int B_HF = (n_hf + 2047) / 2048;   // 8 elems/thread
    hipLaunchKernelGGL(prep_k, dim3(B_HF + 96), dim3(256), 0, stream,
                       hf, W1, W2, hf2, w1t, w2t, n_hf, B_HF);
    hipLaunchKernelGGL(fused_k, dim3(ntiles), dim3(256), 0, stream,
                       hf2, w_q, pi, stats, po, w1t, b1, gamma, beta, w2t, b2, out, H);
}

// Round 3
// 235.140 us; speedup vs baseline: 1.3842x; 1.3842x over previous
//
#include <hip/hip_runtime.h>
#include <hip/hip_bf16.h>
#include <math.h>

#define DIM 128
#define DFF 512
#define TTW 64
#define NPI 8
#define NTOK 9
#define TILE_H 32

typedef __attribute__((ext_vector_type(8))) short short8;
typedef __attribute__((ext_vector_type(4))) float float4v;

__device__ __forceinline__ float bf16lo_f32(unsigned u) {
    union { unsigned u; float f; } v; v.u = u << 16;
    return v.f;
}
__device__ __forceinline__ float bf16hi_f32(unsigned u) {
    union { unsigned u; float f; } v; v.u = u & 0xffff0000u;
    return v.f;
}
__device__ __forceinline__ unsigned pk_bf16(float a, float b) {  // -> a | b<<16
    __hip_bfloat162 h = __float22bfloat162_rn(float2{a, b});
    union { __hip_bfloat162 h; unsigned u; } cv; cv.h = h;
    return cv.u;
}

// ============ prep (slim): hf->bf16 (8 elems/thread) + W1/W2 transposes ============
__global__ __launch_bounds__(256)
void prep_k(const float* __restrict__ hf, const float* __restrict__ W1,
            const float* __restrict__ W2,
            unsigned short* __restrict__ hf2, unsigned short* __restrict__ w1t,
            unsigned short* __restrict__ w2t,
            int n_hf, int B_HF)
{
    __shared__ float tile[32][33];
    const int b = blockIdx.x, t = threadIdx.x;
    if (b < B_HF) {
        int i = (b * 256 + t) * 8;
        if (i < n_hf) {
            float4v v0 = *(const float4v*)(hf + i);
            float4v v1 = *(const float4v*)(hf + i + 4);
            uint4 o;
            o.x = pk_bf16(v0[0], v0[1]);
            o.y = pk_bf16(v0[2], v0[3]);
            o.z = pk_bf16(v1[0], v1[1]);
            o.w = pk_bf16(v1[2], v1[3]);
            *(uint4*)(hf2 + i) = o;
        }
    } else if (b < B_HF + 64) {
        const int tb = b - B_HF;            // W1 [128][512] -> w1t bf16 [512][128]
        const int r0 = (tb & 3) * 32, c0 = (tb >> 2) * 32;
        const int ty = t >> 3, tx = t & 7;
        *(float4v*)&tile[ty][tx * 4] = *(const float4v*)(W1 + (r0 + ty) * DFF + c0 + tx * 4);
        __syncthreads();
        uint2 o;
        o.x = pk_bf16(tile[tx * 4 + 0][ty], tile[tx * 4 + 1][ty]);
        o.y = pk_bf16(tile[tx * 4 + 2][ty], tile[tx * 4 + 3][ty]);
        *(uint2*)(w1t + (c0 + ty) * DIM + r0 + tx * 4) = o;
    } else {
        const int tb = b - B_HF - 64;       // W2 [512][64] -> w2t bf16 [64][512]
        const int r0 = (tb & 15) * 32, c0 = (tb >> 4) * 32;
        const int ty = t >> 3, tx = t & 7;
        *(float4v*)&tile[ty][tx * 4] = *(const float4v*)(W2 + (r0 + ty) * TTW + c0 + tx * 4);
        __syncthreads();
        uint2 o;
        o.x = pk_bf16(tile[tx * 4 + 0][ty], tile[tx * 4 + 1][ty]);
        o.y = pk_bf16(tile[tx * 4 + 2][ty], tile[tx * 4 + 3][ty]);
        *(uint2*)(w2t + (c0 + ty) * DFF + r0 + tx * 4) = o;
    }
}

// ===== fused: gather+pool -> GEMM1 -> reg-LN (packed early) -> k-split GEMM2 =====
// R0: LDS 43008 -> 3 blocks/CU, Occ 30%, latency-bound (MfmaUtil 6.5%), 124 us.
// R1: (256,6) cap ~85 < ~110 demand (gather tu=72, GEMM1 acc+bfr=96+) ->
//     spilled (WRITE 25->465 MB). R2: (256,5) cap ~100 still < demand -> spilled.
// R3: (256,4) cap 128 >= demand -> no spill; occupancy VGPR-bound at 16
//     waves/CU = 50% cap (LDS 26624 would allow 6 blocks). Keep k-split +
//     pk-pre-pack. If WRITE_SIZE > 50 MB again -> drop the cap to (256,3).
__global__ __launch_bounds__(256, 4)
void fused_k(const unsigned short* __restrict__ hf2,
             const float* __restrict__ w_q,
             const int* __restrict__ pi,
             const int* __restrict__ stats,
             const int* __restrict__ po,
             const unsigned short* __restrict__ w1t,     // bf16 [512][128]
             const float* __restrict__ b1,
             const float* __restrict__ gamma,
             const float* __restrict__ beta,
             const unsigned short* __restrict__ w2t,     // bf16 [64][512]
             const float* __restrict__ b2,
             float* __restrict__ out,
             int H)
{
    __shared__ __align__(16) unsigned short Apool[TILE_H][DIM + 8];   // 8704 B
    __shared__ __align__(16) unsigned short Hsm[TILE_H][256 + 8];     // 16896 B
    __shared__ float part[2][16][4][2];                 // [ht][row][wave][sum,ssq]

    const int t    = threadIdx.x;
    const int lane = t & 63;
    const int w    = t >> 6;
    const int row  = lane & 15;
    const int quad = lane >> 4;
    const int hop0 = blockIdx.x * TILE_H;

    // -------- Phase 1: gather + masked attention pooling (32 lanes/hop) --------
    {
        const int g = t >> 5, l = t & 31;       // lane l owns dims 4l..4l+3
        const float4v wq4 = *(const float4v*)(w_q + l * 4);

        int idxs[4][NTOK];
        unsigned vm[4];
        #pragma unroll
        for (int it = 0; it < 4; ++it) {
            int hop = hop0 + g + it * 8;
            if (hop >= H) hop = H - 1;          // clamp; out stores are guarded
            int4 p0 = *(const int4*)(pi + hop * NPI);
            int4 p1 = *(const int4*)(pi + hop * NPI + 4);
            int4 s0 = *(const int4*)(stats + hop * NPI);
            int4 s1 = *(const int4*)(stats + hop * NPI + 4);
            idxs[it][0] = p0.x; idxs[it][1] = p0.y;
            idxs[it][2] = p0.z; idxs[it][3] = p0.w;
            idxs[it][4] = p1.x; idxs[it][5] = p1.y;
            idxs[it][6] = p1.z; idxs[it][7] = p1.w;
            idxs[it][8] = po[hop];
            vm[it] = (s0.x != -1 ? 1u   : 0u) | (s0.y != -1 ? 2u   : 0u)
                   | (s0.z != -1 ? 4u   : 0u) | (s0.w != -1 ? 8u   : 0u)
                   | (s1.x != -1 ? 16u  : 0u) | (s1.y != -1 ? 32u  : 0u)
                   | (s1.z != -1 ? 64u  : 0u) | (s1.w != -1 ? 128u : 0u)
                   | 256u;                      // PO always valid
        }
        uint2 tu[4][NTOK];
        #pragma unroll
        for (int it = 0; it < 4; ++it)
            #pragma unroll
            for (int p = 0; p < NTOK; ++p)
                tu[it][p] = *(const uint2*)(hf2 + (size_t)idxs[it][p] * DIM + l * 4);

        #pragma unroll
        for (int it = 0; it < 4; ++it) {
            const int hl = g + it * 8;
            float tok[NTOK][4];
            #pragma unroll
            for (int p = 0; p < NTOK; ++p) {
                tok[p][0] = bf16lo_f32(tu[it][p].x);
                tok[p][1] = bf16hi_f32(tu[it][p].x);
                tok[p][2] = bf16lo_f32(tu[it][p].y);
                tok[p][3] = bf16hi_f32(tu[it][p].y);
            }
            float sc[NTOK];
            #pragma unroll
            for (int p = 0; p < NTOK; ++p)
                sc[p] = tok[p][0]*wq4[0] + tok[p][1]*wq4[1]
                      + tok[p][2]*wq4[2] + tok[p][3]*wq4[3];
            #pragma unroll
            for (int m = 1; m < 32; m <<= 1) {
                #pragma unroll
                for (int p = 0; p < NTOK; ++p) sc[p] += __shfl_xor(sc[p], m);
            }
            const float isd = 0.08838834764831845f;   // 1/sqrt(128)
            float mx = -1e30f;
            #pragma unroll
            for (int p = 0; p < NTOK; ++p) {
                sc[p] = ((vm[it] >> p) & 1u) ? sc[p] * isd : -1e30f;
                mx = fmaxf(mx, sc[p]);
            }
            float se = 0.f;
            #pragma unroll
            for (int p = 0; p < NTOK; ++p) { sc[p] = __expf(sc[p] - mx); se += sc[p]; }
            const float inv = 1.f / se;
            float a0=0.f, a1=0.f, a2=0.f, a3=0.f;
            #pragma unroll
            for (int p = 0; p < NTOK; ++p) {
                float a = sc[p] * inv;
                a0 += a * tok[p][0]; a1 += a * tok[p][1];
                a2 += a * tok[p][2]; a3 += a * tok[p][3];
            }
            uint2 o;
            o.x = pk_bf16(a0, a1);
            o.y = pk_bf16(a2, a3);
            *(uint2*)&Apool[hl][l * 4] = o;
        }
    }
    __syncthreads();

    // -------- GEMM1: A=W1T rows (out-dims, striped mt*64+w*16), B=Apool^T --------
    float4v acc[8][2];
    #pragma unroll
    for (int mt = 0; mt < 8; ++mt) {
        acc[mt][0] = (float4v){0.f, 0.f, 0.f, 0.f};
        acc[mt][1] = (float4v){0.f, 0.f, 0.f, 0.f};
    }
    {
        short8 bfr[2][4];
        #pragma unroll
        for (int ks = 0; ks < 4; ++ks) {
            const int k0 = ks * 32 + quad * 8;
            #pragma unroll
            for (int ht = 0; ht < 2; ++ht)
                bfr[ht][ks] = *(const short8*)&Apool[ht * 16 + row][k0];
        }
        #pragma unroll
        for (int mt = 0; mt < 8; ++mt) {
            const unsigned short* wrow = w1t + (size_t)(mt * 64 + w * 16 + row) * DIM;
            #pragma unroll
            for (int ks = 0; ks < 4; ++ks) {
                short8 afr = *(const short8*)(wrow + ks * 32 + quad * 8);
                acc[mt][0] = __builtin_amdgcn_mfma_f32_16x16x32_bf16(afr, bfr[0][ks], acc[mt][0], 0, 0, 0);
                acc[mt][1] = __builtin_amdgcn_mfma_f32_16x16x32_bf16(afr, bfr[1][ks], acc[mt][1], 0, 0, 0);
            }
        }
    }
    // -------- pass 1: bias + ReLU in registers, LN stats --------
    float sum0 = 0.f, ssq0 = 0.f, sum1 = 0.f, ssq1 = 0.f;
    #pragma unroll
    for (int mt = 0; mt < 8; ++mt) {
        const int nb = mt * 64 + w * 16 + quad * 4;
        const float4v bias = *(const float4v*)(b1 + nb);
        #pragma unroll
        for (int r = 0; r < 4; ++r) {
            float v0 = fmaxf(acc[mt][0][r] + bias[r], 0.f);
            float v1 = fmaxf(acc[mt][1][r] + bias[r], 0.f);
            acc[mt][0][r] = v0;  sum0 += v0;  ssq0 += v0 * v0;
            acc[mt][1][r] = v1;  sum1 += v1;  ssq1 += v1 * v1;
        }
    }
    #pragma unroll
    for (int m = 16; m <= 32; m <<= 1) {       // reduce across the 4 quads
        sum0 += __shfl_xor(sum0, m);  ssq0 += __shfl_xor(ssq0, m);
        sum1 += __shfl_xor(sum1, m);  ssq1 += __shfl_xor(ssq1, m);
    }
    if (lane < 16) {
        part[0][row][w][0] = sum0;  part[0][row][w][1] = ssq0;
        part[1][row][w][0] = sum1;  part[1][row][w][1] = ssq1;
    }
    __syncthreads();
    float mu[2], rs[2];
    #pragma unroll
    for (int ht = 0; ht < 2; ++ht) {
        float S = 0.f, Q = 0.f;
        #pragma unroll
        for (int ww = 0; ww < 4; ++ww) {
            S += part[ht][row][ww][0];
            Q += part[ht][row][ww][1];
        }
        const float invn = 1.f / (float)DFF;
        mu[ht] = S * invn;
        float var = Q * invn - mu[ht] * mu[ht];
        rs[ht] = rsqrtf(var + 1e-5f);
    }
    // -------- pass 2: normalize ALL dims now, pack bf16 -> pk[8][2] (32 regs);
    //          fp32 acc (64 regs) dies here, BEFORE the chunk loop. --------
    uint2 pk[8][2];
    #pragma unroll
    for (int mt = 0; mt < 8; ++mt) {
        const int nb = mt * 64 + w * 16 + quad * 4;
        const float4v g4  = *(const float4v*)(gamma + nb);
        const float4v be4 = *(const float4v*)(beta + nb);
        #pragma unroll
        for (int ht = 0; ht < 2; ++ht) {
            float o[4];
            #pragma unroll
            for (int r = 0; r < 4; ++r) {
                float tg = rs[ht] * g4[r];
                o[r] = acc[mt][ht][r] * tg + (be4[r] - mu[ht] * tg);
            }
            pk[mt][ht].x = pk_bf16(o[0], o[1]);
            pk[mt][ht].y = pk_bf16(o[2], o[3]);
        }
    }
    // -------- GEMM2, k-split into two 256-wide chunks through half-width Hsm ----
    {
        float4v acc2[2];
        acc2[0] = (float4v){0.f,0.f,0.f,0.f};
        acc2[1] = (float4v){0.f,0.f,0.f,0.f};
        #pragma unroll
        for (int c = 0; c < 2; ++c) {
            #pragma unroll
            for (int m4 = 0; m4 < 4; ++m4) {
                const int col = m4 * 64 + w * 16 + quad * 4;    // col within chunk
                *(uint2*)&Hsm[0 * 16 + row][col] = pk[c * 4 + m4][0];
                *(uint2*)&Hsm[1 * 16 + row][col] = pk[c * 4 + m4][1];
            }
            __syncthreads();
            // accumulate this k-chunk: A=Hsm [hop][k] LDS, B=w2t [tt][k] global
            const unsigned short* w2row = w2t + (size_t)(w * 16 + row) * DFF + c * 256;
            #pragma unroll
            for (int ks = 0; ks < 8; ++ks) {
                const int k0 = ks * 32 + quad * 8;
                short8 bfr = *(const short8*)(w2row + k0);
                #pragma unroll
                for (int mt = 0; mt < 2; ++mt) {
                    short8 afr = *(const short8*)&Hsm[mt * 16 + row][k0];
                    acc2[mt] = __builtin_amdgcn_mfma_f32_16x16x32_bf16(
                        afr, bfr, acc2[mt], 0, 0, 0);
                }
            }
            if (c == 0) __syncthreads();   // all reads done before chunk-1 writes
        }
        const float bb = b2[w * 16 + row];
        #pragma unroll
        for (int mt = 0; mt < 2; ++mt) {
            #pragma unroll
            for (int r = 0; r < 4; ++r) {
                int hop = hop0 + mt * 16 + quad * 4 + r;
                if (hop < H)
                    out[(size_t)hop * TTW + w * 16 + row] = acc2[mt][r] + bb;
            }
        }
    }
}

extern "C" void kernel_launch(void* const* d_in, const int* in_sizes, int n_in,
                              void* d_out, int out_size, void* d_ws, size_t ws_size,
                              hipStream_t stream) {
    const float* hf    = (const float*)d_in[0];
    const float* w_q   = (const float*)d_in[1];
    const float* W1    = (const float*)d_in[2];
    const float* b1    = (const float*)d_in[3];
    const float* gamma = (const float*)d_in[4];
    const float* beta  = (const float*)d_in[5];
    const float* W2    = (const float*)d_in[6];
    const float* b2    = (const float*)d_in[7];
    const int* pi      = (const int*)d_in[8];
    const int* stats   = (const int*)d_in[9];
    const int* po      = (const int*)d_in[10];
    float* out         = (float*)d_out;

    const int n_hf = in_sizes[0];           // N_NODES*128
    const int H    = in_sizes[10];
    const int ntiles = (H + TILE_H - 1) / TILE_H;

    // ws layout
    char* ws = (char*)d_ws;
    unsigned short* w1t = (unsigned short*)ws;                       // 128KB
    unsigned short* w2t = (unsigned short*)(ws + 131072);            // 64KB
    unsigned short* hf2 = (unsigned short*)(ws + 196608);            // n_hf*2

    const int B_HF = (n_hf + 2047) / 2048;   // 8 elems/thread
    hipLaunchKernelGGL(prep_k, dim3(B_HF + 96), dim3(256), 0, stream,
                       hf, W1, W2, hf2, w1t, w2t, n_hf, B_HF);
    hipLaunchKernelGGL(fused_k, dim3(ntiles), dim3(256), 0, stream,
                       hf2, w_q, pi, stats, po, w1t, b1, gamma, beta, w2t, b2, out, H);
}

// Round 4
// 225.571 us; speedup vs baseline: 1.4429x; 1.0424x over previous
//
#include <hip/hip_runtime.h>
#include <hip/hip_bf16.h>
#include <math.h>

#define DIM 128
#define DFF 512
#define TTW 64
#define NPI 8
#define NTOK 9
#define TILE_H 32

typedef __attribute__((ext_vector_type(8))) short short8;
typedef __attribute__((ext_vector_type(4))) float float4v;

__device__ __forceinline__ float bf16lo_f32(unsigned u) {
    union { unsigned u; float f; } v; v.u = u << 16;
    return v.f;
}
__device__ __forceinline__ float bf16hi_f32(unsigned u) {
    union { unsigned u; float f; } v; v.u = u & 0xffff0000u;
    return v.f;
}
__device__ __forceinline__ unsigned pk_bf16(float a, float b) {  // -> a | b<<16
    __hip_bfloat162 h = __float22bfloat162_rn(float2{a, b});
    union { __hip_bfloat162 h; unsigned u; } cv; cv.h = h;
    return cv.u;
}

// ==== prep: hf->bf16, W1 transpose, gamma-folded W2 transpose, C1/C2 vectors ====
// LN-fold: logits = rs*(h_raw @ (g.*W2)) - rs*mu*C1 + C2,
//   C1[t] = sum_k g[k]*W2[k][t],  C2[t] = b2[t] + sum_k be[k]*W2[k][t].
__global__ __launch_bounds__(256)
void prep_k(const float* __restrict__ hf, const float* __restrict__ W1,
            const float* __restrict__ W2, const float* __restrict__ gamma,
            const float* __restrict__ beta, const float* __restrict__ b2,
            unsigned short* __restrict__ hf2, unsigned short* __restrict__ w1t,
            unsigned short* __restrict__ w2g,
            float* __restrict__ C1, float* __restrict__ C2,
            int n_hf, int B_HF)
{
    __shared__ float tile[32][33];
    const int b = blockIdx.x, t = threadIdx.x;
    if (b < B_HF) {
        int i = (b * 256 + t) * 8;
        if (i < n_hf) {
            float4v v0 = *(const float4v*)(hf + i);
            float4v v1 = *(const float4v*)(hf + i + 4);
            uint4 o;
            o.x = pk_bf16(v0[0], v0[1]);
            o.y = pk_bf16(v0[2], v0[3]);
            o.z = pk_bf16(v1[0], v1[1]);
            o.w = pk_bf16(v1[2], v1[3]);
            *(uint4*)(hf2 + i) = o;
        }
    } else if (b < B_HF + 64) {
        const int tb = b - B_HF;            // W1 [128][512] -> w1t bf16 [512][128]
        const int r0 = (tb & 3) * 32, c0 = (tb >> 2) * 32;
        const int ty = t >> 3, tx = t & 7;
        *(float4v*)&tile[ty][tx * 4] = *(const float4v*)(W1 + (r0 + ty) * DFF + c0 + tx * 4);
        __syncthreads();
        uint2 o;
        o.x = pk_bf16(tile[tx * 4 + 0][ty], tile[tx * 4 + 1][ty]);
        o.y = pk_bf16(tile[tx * 4 + 2][ty], tile[tx * 4 + 3][ty]);
        *(uint2*)(w1t + (c0 + ty) * DIM + r0 + tx * 4) = o;
    } else if (b < B_HF + 96) {
        const int tb = b - B_HF - 64;       // W2 [512][64] -> w2g bf16 [64][512], *gamma[k]
        const int r0 = (tb & 15) * 32, c0 = (tb >> 4) * 32;
        const int ty = t >> 3, tx = t & 7;
        const float g = gamma[r0 + ty];     // k = r0 + ty
        float4v v = *(const float4v*)(W2 + (r0 + ty) * TTW + c0 + tx * 4);
        v[0] *= g; v[1] *= g; v[2] *= g; v[3] *= g;
        *(float4v*)&tile[ty][tx * 4] = v;
        __syncthreads();
        uint2 o;
        o.x = pk_bf16(tile[tx * 4 + 0][ty], tile[tx * 4 + 1][ty]);
        o.y = pk_bf16(tile[tx * 4 + 2][ty], tile[tx * 4 + 3][ty]);
        *(uint2*)(w2g + (c0 + ty) * DFF + r0 + tx * 4) = o;
    } else {
        // C1/C2: lanes 0..63, tt = t; k-loop is coalesced across lanes
        if (t < TTW) {
            float c1 = 0.f, c2 = 0.f;
            for (int k = 0; k < DFF; ++k) {
                float w = W2[k * TTW + t];
                c1 += gamma[k] * w;
                c2 += beta[k] * w;
            }
            C1[t] = c1;
            C2[t] = b2[t] + c2;
        }
    }
}

// ===== fused: gather+pool -> GEMM1 -> LN-folded pack -> k-split GEMM2 =====
// R0: LDS 43008 -> 3 blk/CU, Occ 30%, latency-bound, 124 us (VGPR 68, no spill).
// R1-R3: __launch_bounds__ 2nd arg caps VGPR at ~256/N (measured: N=6->40,
//   N=5->48, N=4->64) -> any N>=4 spills this kernel (demand ~85-110).
// R4: keep k-split LDS (26624+256) + proven cap (256,3) (~85, R0-safe). LN is
//   folded into W2 (w2g = gamma.*W2; epilogue: rs*(acc2 - mu*C1) + C2), which
//   deletes pass-2 and lets fp32 acc die inside pass-1. Occupancy now
//   VGPR-bound: 4 blk/CU = 16 waves/CU (50% cap) vs R0's 3 blk (37.5%).
__global__ __launch_bounds__(256, 3)
void fused_k(const unsigned short* __restrict__ hf2,
             const float* __restrict__ w_q,
             const int* __restrict__ pi,
             const int* __restrict__ stats,
             const int* __restrict__ po,
             const unsigned short* __restrict__ w1t,     // bf16 [512][128]
             const float* __restrict__ b1,
             const unsigned short* __restrict__ w2g,     // bf16 [64][512] (gamma-folded)
             const float* __restrict__ C1,
             const float* __restrict__ C2,
             float* __restrict__ out,
             int H)
{
    __shared__ __align__(16) unsigned short Apool[TILE_H][DIM + 8];   // 8704 B
    __shared__ __align__(16) unsigned short Hsm[TILE_H][256 + 8];     // 16896 B
    __shared__ float part[2][16][4][2];                 // [ht][row][wave][sum,ssq]
    __shared__ float2 mursm[TILE_H];                    // {mu, rs} per hop, 256 B

    const int t    = threadIdx.x;
    const int lane = t & 63;
    const int w    = t >> 6;
    const int row  = lane & 15;
    const int quad = lane >> 4;
    const int hop0 = blockIdx.x * TILE_H;

    // -------- Phase 1: gather + masked attention pooling (32 lanes/hop) --------
    {
        const int g = t >> 5, l = t & 31;       // lane l owns dims 4l..4l+3
        const float4v wq4 = *(const float4v*)(w_q + l * 4);

        int idxs[4][NTOK];
        unsigned vm[4];
        #pragma unroll
        for (int it = 0; it < 4; ++it) {
            int hop = hop0 + g + it * 8;
            if (hop >= H) hop = H - 1;          // clamp; out stores are guarded
            int4 p0 = *(const int4*)(pi + hop * NPI);
            int4 p1 = *(const int4*)(pi + hop * NPI + 4);
            int4 s0 = *(const int4*)(stats + hop * NPI);
            int4 s1 = *(const int4*)(stats + hop * NPI + 4);
            idxs[it][0] = p0.x; idxs[it][1] = p0.y;
            idxs[it][2] = p0.z; idxs[it][3] = p0.w;
            idxs[it][4] = p1.x; idxs[it][5] = p1.y;
            idxs[it][6] = p1.z; idxs[it][7] = p1.w;
            idxs[it][8] = po[hop];
            vm[it] = (s0.x != -1 ? 1u   : 0u) | (s0.y != -1 ? 2u   : 0u)
                   | (s0.z != -1 ? 4u   : 0u) | (s0.w != -1 ? 8u   : 0u)
                   | (s1.x != -1 ? 16u  : 0u) | (s1.y != -1 ? 32u  : 0u)
                   | (s1.z != -1 ? 64u  : 0u) | (s1.w != -1 ? 128u : 0u)
                   | 256u;                      // PO always valid
        }
        uint2 tu[4][NTOK];
        #pragma unroll
        for (int it = 0; it < 4; ++it)
            #pragma unroll
            for (int p = 0; p < NTOK; ++p)
                tu[it][p] = *(const uint2*)(hf2 + (size_t)idxs[it][p] * DIM + l * 4);

        #pragma unroll
        for (int it = 0; it < 4; ++it) {
            const int hl = g + it * 8;
            float tok[NTOK][4];
            #pragma unroll
            for (int p = 0; p < NTOK; ++p) {
                tok[p][0] = bf16lo_f32(tu[it][p].x);
                tok[p][1] = bf16hi_f32(tu[it][p].x);
                tok[p][2] = bf16lo_f32(tu[it][p].y);
                tok[p][3] = bf16hi_f32(tu[it][p].y);
            }
            float sc[NTOK];
            #pragma unroll
            for (int p = 0; p < NTOK; ++p)
                sc[p] = tok[p][0]*wq4[0] + tok[p][1]*wq4[1]
                      + tok[p][2]*wq4[2] + tok[p][3]*wq4[3];
            #pragma unroll
            for (int m = 1; m < 32; m <<= 1) {
                #pragma unroll
                for (int p = 0; p < NTOK; ++p) sc[p] += __shfl_xor(sc[p], m);
            }
            const float isd = 0.08838834764831845f;   // 1/sqrt(128)
            float mx = -1e30f;
            #pragma unroll
            for (int p = 0; p < NTOK; ++p) {
                sc[p] = ((vm[it] >> p) & 1u) ? sc[p] * isd : -1e30f;
                mx = fmaxf(mx, sc[p]);
            }
            float se = 0.f;
            #pragma unroll
            for (int p = 0; p < NTOK; ++p) { sc[p] = __expf(sc[p] - mx); se += sc[p]; }
            const float inv = 1.f / se;
            float a0=0.f, a1=0.f, a2=0.f, a3=0.f;
            #pragma unroll
            for (int p = 0; p < NTOK; ++p) {
                float a = sc[p] * inv;
                a0 += a * tok[p][0]; a1 += a * tok[p][1];
                a2 += a * tok[p][2]; a3 += a * tok[p][3];
            }
            uint2 o;
            o.x = pk_bf16(a0, a1);
            o.y = pk_bf16(a2, a3);
            *(uint2*)&Apool[hl][l * 4] = o;
        }
    }
    __syncthreads();

    // -------- GEMM1: A=W1T rows (out-dims, striped mt*64+w*16), B=Apool^T --------
    float4v acc[8][2];
    #pragma unroll
    for (int mt = 0; mt < 8; ++mt) {
        acc[mt][0] = (float4v){0.f, 0.f, 0.f, 0.f};
        acc[mt][1] = (float4v){0.f, 0.f, 0.f, 0.f};
    }
    {
        short8 bfr[2][4];
        #pragma unroll
        for (int ks = 0; ks < 4; ++ks) {
            const int k0 = ks * 32 + quad * 8;
            #pragma unroll
            for (int ht = 0; ht < 2; ++ht)
                bfr[ht][ks] = *(const short8*)&Apool[ht * 16 + row][k0];
        }
        #pragma unroll
        for (int mt = 0; mt < 8; ++mt) {
            const unsigned short* wrow = w1t + (size_t)(mt * 64 + w * 16 + row) * DIM;
            #pragma unroll
            for (int ks = 0; ks < 4; ++ks) {
                short8 afr = *(const short8*)(wrow + ks * 32 + quad * 8);
                acc[mt][0] = __builtin_amdgcn_mfma_f32_16x16x32_bf16(afr, bfr[0][ks], acc[mt][0], 0, 0, 0);
                acc[mt][1] = __builtin_amdgcn_mfma_f32_16x16x32_bf16(afr, bfr[1][ks], acc[mt][1], 0, 0, 0);
            }
        }
    }
    // -------- pass 1: bias + ReLU, LN stats, pack PRE-LN h to bf16 (acc dies) ----
    float sum0 = 0.f, ssq0 = 0.f, sum1 = 0.f, ssq1 = 0.f;
    uint2 pk[8][2];
    #pragma unroll
    for (int mt = 0; mt < 8; ++mt) {
        const int nb = mt * 64 + w * 16 + quad * 4;
        const float4v bias = *(const float4v*)(b1 + nb);
        float o0[4], o1[4];
        #pragma unroll
        for (int r = 0; r < 4; ++r) {
            o0[r] = fmaxf(acc[mt][0][r] + bias[r], 0.f);
            o1[r] = fmaxf(acc[mt][1][r] + bias[r], 0.f);
            sum0 += o0[r];  ssq0 += o0[r] * o0[r];
            sum1 += o1[r];  ssq1 += o1[r] * o1[r];
        }
        pk[mt][0].x = pk_bf16(o0[0], o0[1]);  pk[mt][0].y = pk_bf16(o0[2], o0[3]);
        pk[mt][1].x = pk_bf16(o1[0], o1[1]);  pk[mt][1].y = pk_bf16(o1[2], o1[3]);
    }
    #pragma unroll
    for (int m = 16; m <= 32; m <<= 1) {       // reduce across the 4 quads
        sum0 += __shfl_xor(sum0, m);  ssq0 += __shfl_xor(ssq0, m);
        sum1 += __shfl_xor(sum1, m);  ssq1 += __shfl_xor(ssq1, m);
    }
    if (lane < 16) {
        part[0][row][w][0] = sum0;  part[0][row][w][1] = ssq0;
        part[1][row][w][0] = sum1;  part[1][row][w][1] = ssq1;
    }
    __syncthreads();
    {
        const float invn = 1.f / (float)DFF;
        float mu0, rs0, mu1, rs1;
        {
            float S = 0.f, Q = 0.f;
            #pragma unroll
            for (int ww = 0; ww < 4; ++ww) { S += part[0][row][ww][0]; Q += part[0][row][ww][1]; }
            mu0 = S * invn;  rs0 = rsqrtf(Q * invn - mu0 * mu0 + 1e-5f);
        }
        {
            float S = 0.f, Q = 0.f;
            #pragma unroll
            for (int ww = 0; ww < 4; ++ww) { S += part[1][row][ww][0]; Q += part[1][row][ww][1]; }
            mu1 = S * invn;  rs1 = rsqrtf(Q * invn - mu1 * mu1 + 1e-5f);
        }
        if (t < 16) {                          // wave 0, quad 0: row == t
            mursm[t]      = float2{mu0, rs0};
            mursm[16 + t] = float2{mu1, rs1};
        }
    }
    // -------- GEMM2, k-split into two 256-wide chunks through half-width Hsm ----
    {
        float4v acc2[2];
        acc2[0] = (float4v){0.f,0.f,0.f,0.f};
        acc2[1] = (float4v){0.f,0.f,0.f,0.f};
        #pragma unroll
        for (int c = 0; c < 2; ++c) {
            #pragma unroll
            for (int m4 = 0; m4 < 4; ++m4) {
                const int col = m4 * 64 + w * 16 + quad * 4;    // col within chunk
                *(uint2*)&Hsm[0 * 16 + row][col] = pk[c * 4 + m4][0];
                *(uint2*)&Hsm[1 * 16 + row][col] = pk[c * 4 + m4][1];
            }
            __syncthreads();
            // accumulate this k-chunk: A=Hsm [hop][k] LDS, B=w2g [tt][k] global
            const unsigned short* w2row = w2g + (size_t)(w * 16 + row) * DFF + c * 256;
            #pragma unroll
            for (int ks = 0; ks < 8; ++ks) {
                const int k0 = ks * 32 + quad * 8;
                short8 bfr = *(const short8*)(w2row + k0);
                #pragma unroll
                for (int mt = 0; mt < 2; ++mt) {
                    short8 afr = *(const short8*)&Hsm[mt * 16 + row][k0];
                    acc2[mt] = __builtin_amdgcn_mfma_f32_16x16x32_bf16(
                        afr, bfr, acc2[mt], 0, 0, 0);
                }
            }
            if (c == 0) __syncthreads();   // all reads done before chunk-1 writes
        }
        // epilogue: LN applied algebraically: rs*(acc2 - mu*C1[tt]) + C2[tt]
        const int tt = w * 16 + row;
        const float c1v = C1[tt];
        const float c2v = C2[tt];
        #pragma unroll
        for (int mt = 0; mt < 2; ++mt) {
            #pragma unroll
            for (int r = 0; r < 4; ++r) {
                const int hl = mt * 16 + quad * 4 + r;
                int hop = hop0 + hl;
                if (hop < H) {
                    float2 mr = mursm[hl];     // {mu, rs}
                    out[(size_t)hop * TTW + tt] = mr.y * (acc2[mt][r] - mr.x * c1v) + c2v;
                }
            }
        }
    }
}

extern "C" void kernel_launch(void* const* d_in, const int* in_sizes, int n_in,
                              void* d_out, int out_size, void* d_ws, size_t ws_size,
                              hipStream_t stream) {
    const float* hf    = (const float*)d_in[0];
    const float* w_q   = (const float*)d_in[1];
    const float* W1    = (const float*)d_in[2];
    const float* b1    = (const float*)d_in[3];
    const float* gamma = (const float*)d_in[4];
    const float* beta  = (const float*)d_in[5];
    const float* W2    = (const float*)d_in[6];
    const float* b2    = (const float*)d_in[7];
    const int* pi      = (const int*)d_in[8];
    const int* stats   = (const int*)d_in[9];
    const int* po      = (const int*)d_in[10];
    float* out         = (float*)d_out;

    const int n_hf = in_sizes[0];           // N_NODES*128
    const int H    = in_sizes[10];
    const int ntiles = (H + TILE_H - 1) / TILE_H;

    // ws layout: w1t 128KB | w2g 64KB | hf2 n_hf*2 | C1 256B | C2 256B
    char* ws = (char*)d_ws;
    unsigned short* w1t = (unsigned short*)ws;                       // 131072 B
    unsigned short* w2g = (unsigned short*)(ws + 131072);            // 65536 B
    unsigned short* hf2 = (unsigned short*)(ws + 196608);            // n_hf*2 B
    float* C1 = (float*)(ws + 196608 + (size_t)n_hf * 2);            // 256 B
    float* C2 = C1 + TTW;                                            // 256 B

    const int B_HF = (n_hf + 2047) / 2048;   // 8 elems/thread
    hipLaunchKernelGGL(prep_k, dim3(B_HF + 97), dim3(256), 0, stream,
                       hf, W1, W2, gamma, beta, b2, hf2, w1t, w2g, C1, C2, n_hf, B_HF);
    hipLaunchKernelGGL(fused_k, dim3(ntiles), dim3(256), 0, stream,
                       hf2, w_q, pi, stats, po, w1t, b1, w2g, C1, C2, out, H);
}